// Round 10
// baseline (267.569 us; speedup 1.0000x reference)
//
#include <hip/hip_runtime.h>
#include <hip/hip_cooperative_groups.h>
#include <math.h>

namespace cg = cooperative_groups;

#define SEQ 256
#define DIMC 512
#define SCALEF 0.125f
#define PSTR 264
#define KSTR 72
#define RSTRIDE 280

typedef __attribute__((ext_vector_type(8))) short s16x8;
typedef __attribute__((ext_vector_type(4))) float f32x4;

typedef __attribute__((address_space(3))) unsigned int lds_u32_t;
typedef const __attribute__((address_space(1))) unsigned int g_u32_t;
static __device__ __forceinline__ void gl_lds16(const void* gsrc, void* ldst) {
  __builtin_amdgcn_global_load_lds((g_u32_t*)gsrc, (lds_u32_t*)ldst, 16, 0, 0);
}

static __device__ __forceinline__ unsigned short f2bf(float f) {
  union { float f; unsigned u; } c; c.f = f;
  unsigned r = c.u + 0x7FFF + ((c.u >> 16) & 1);  // RNE
  return (unsigned short)(r >> 16);
}
static __device__ __forceinline__ float bf2f(unsigned short u) {
  union { unsigned u; float f; } c; c.u = ((unsigned)u) << 16;
  return c.f;
}

// ---------------- P0 helper: one 64x64 tcast tile (fp32 W[KxN]->bf16 WT[NxK])
static __device__ void tcast_tile(const float* __restrict__ W,
    unsigned short* __restrict__ WT, int K, int N, int n0, int k0, int t,
    unsigned char* smem) {
  float (*tile)[65] = (float(*)[65])smem;
#pragma unroll
  for (int i = 0; i < 16; ++i) {
    const int idx = i * 256 + t;
    const int kl = idx >> 6, nl = idx & 63;
    tile[kl][nl] = W[(size_t)(k0 + kl) * N + n0 + nl];
  }
  __syncthreads();
#pragma unroll
  for (int i = 0; i < 16; ++i) {
    const int idx = i * 256 + t;
    const int nl = idx >> 6, kl = idx & 63;
    WT[(size_t)(n0 + nl) * K + k0 + kl] = f2bf(tile[kl][nl]);
  }
  __syncthreads();  // protect LDS reuse by next task
}

// ---------------- P1/P4 helper: one 64x64 GEMM tile, BK=64 -------------------
// XOR swizzle: LDS phys chunk (row,jp) holds logical chunk jp^(row&7).
template <bool OUTBF, bool BIAS, bool VSPLIT>
static __device__ void gemm_tile(const unsigned short* __restrict__ A,
    const unsigned short* __restrict__ BT, const float* __restrict__ bias,
    void* __restrict__ Cv, unsigned short* __restrict__ vtb,
    int bm, int bn, int K, int N, int t, unsigned char* smem) {
  unsigned short* As = (unsigned short*)smem;
  unsigned short* Bs = As + 64 * 64;
  const int wave = t >> 6, lane = t & 63;
  const int wr = wave >> 1, wc = wave & 1;
  const int fr = lane & 15, q4 = lane >> 4;
  f32x4 acc[2][2] = {};
  const int kBlocks = K >> 6;
  for (int kb = 0; kb < kBlocks; ++kb) {
    const int k0 = kb << 6;
    __syncthreads();
#pragma unroll
    for (int c = 0; c < 2; ++c) {
      const int p = c * 256 + t;
      const int row = p >> 3;
      const int jl = (p & 7) ^ (row & 7);
      gl_lds16(A + (size_t)(bm + row) * K + k0 + jl * 8,
               As + (size_t)(c * 256 + wave * 64) * 8);
    }
#pragma unroll
    for (int c = 0; c < 2; ++c) {
      const int p = c * 256 + t;
      const int row = p >> 3;
      const int jl = (p & 7) ^ (row & 7);
      gl_lds16(BT + (size_t)(bn + row) * K + k0 + jl * 8,
               Bs + (size_t)(c * 256 + wave * 64) * 8);
    }
    __syncthreads();
    s16x8 af[2][2], bfr[2][2];
#pragma unroll
    for (int i = 0; i < 2; ++i)
#pragma unroll
      for (int ks = 0; ks < 2; ++ks) {
        const int row = wr * 32 + i * 16 + fr;
        const int jp = (ks * 4 + q4) ^ (fr & 7);
        af[i][ks] = *(const s16x8*)(As + row * 64 + jp * 8);
      }
#pragma unroll
    for (int j = 0; j < 2; ++j)
#pragma unroll
      for (int ks = 0; ks < 2; ++ks) {
        const int row = wc * 32 + j * 16 + fr;
        const int jp = (ks * 4 + q4) ^ (fr & 7);
        bfr[j][ks] = *(const s16x8*)(Bs + row * 64 + jp * 8);
      }
#pragma unroll
    for (int ks = 0; ks < 2; ++ks)
#pragma unroll
      for (int i = 0; i < 2; ++i)
#pragma unroll
        for (int j = 0; j < 2; ++j)
          acc[i][j] = __builtin_amdgcn_mfma_f32_16x16x32_bf16(
              af[i][ks], bfr[j][ks], acc[i][j], 0, 0, 0);
  }
  if (VSPLIT && bn >= 1024) {
#pragma unroll
    for (int i = 0; i < 2; ++i)
#pragma unroll
      for (int j = 0; j < 2; ++j) {
        const int hc = bn - 1024 + wc * 32 + j * 16 + fr;
        const int h = hc >> 6, d = hc & 63;
#pragma unroll
        for (int r = 0; r < 4; ++r) {
          const int row = bm + wr * 32 + i * 16 + q4 * 4 + r;
          const int b = row >> 8, m = row & 255;
          vtb[(size_t)((b * 8 + h) * 64 + d) * 256 + m] = f2bf(acc[i][j][r]);
        }
      }
    return;
  }
#pragma unroll
  for (int i = 0; i < 2; ++i)
#pragma unroll
    for (int j = 0; j < 2; ++j) {
      const int col = bn + wc * 32 + j * 16 + fr;
      const float bv = BIAS ? bias[col] : 0.0f;
#pragma unroll
      for (int r = 0; r < 4; ++r) {
        const int row = bm + wr * 32 + i * 16 + q4 * 4 + r;
        if constexpr (OUTBF) {
          ((unsigned short*)Cv)[(size_t)row * N + col] = f2bf(acc[i][j][r] + bv);
        } else {
          ((float*)Cv)[(size_t)row * N + col] = acc[i][j][r] + bv;
        }
      }
    }
}

// ---------------- The cooperative mega-kernel --------------------------------
__global__ __launch_bounds__(256) void mega_kernel(
    const float* __restrict__ x, const float* __restrict__ g,
    const float* __restrict__ bta, const float* __restrict__ w_qkv,
    const float* __restrict__ w_out, const float* __restrict__ b_out,
    const float* __restrict__ up, float* __restrict__ out,
    unsigned short* __restrict__ xnb, unsigned short* __restrict__ wqt,
    unsigned short* __restrict__ wot, unsigned short* __restrict__ upb,
    unsigned short* __restrict__ qkvb, unsigned short* __restrict__ vtb,
    unsigned short* __restrict__ attnb, unsigned short* __restrict__ ob) {
  cg::grid_group grid = cg::this_grid();
  __shared__ alignas(16) unsigned char smem[70656];
  const int t = threadIdx.x;
  const int bid = blockIdx.x;
  const int wave = t >> 6, lane = t & 63;
  const int fr = lane & 15, q4 = lane >> 4;

  // ===== P0: prep (wqt tcast 192 | wot tcast 64 | up cast 241 | LN 2048) =====
  for (int task = bid; task < 2545; task += 256) {
    if (task < 192) {
      tcast_tile(w_qkv, wqt, 512, 1536, (task % 24) * 64, (task / 24) * 64, t, smem);
    } else if (task < 256) {
      const int b2 = task - 192;
      tcast_tile(w_out, wot, 512, 512, (b2 % 8) * 64, (b2 / 8) * 64, t, smem);
    } else if (task < 497) {
      const int base = (task - 256) * 2048 + t * 4;
#pragma unroll
      for (int it = 0; it < 2; ++it) {
        const int i = base + it * 1024;
        if (i < 492032) {
          const float4 v = *(const float4*)&up[i];
          ushort4 w;
          w.x = f2bf(v.x); w.y = f2bf(v.y); w.z = f2bf(v.z); w.w = f2bf(v.w);
          *(ushort4*)&upb[i] = w;
        }
      }
    } else {
      const int row = task - 497;
      float* sh = (float*)smem;  // 8 floats
      const float2 v = ((const float2*)(x + (size_t)row * DIMC))[t];
      float s = v.x + v.y;
      float q = v.x * v.x + v.y * v.y;
#pragma unroll
      for (int off = 32; off > 0; off >>= 1) {
        s += __shfl_down(s, off);
        q += __shfl_down(q, off);
      }
      if (lane == 0) { sh[wave] = s; sh[4 + wave] = q; }
      __syncthreads();
      const float fs = sh[0] + sh[1] + sh[2] + sh[3];
      const float fq = sh[4] + sh[5] + sh[6] + sh[7];
      const float mean = fs * (1.0f / DIMC);
      const float inv = rsqrtf(fq * (1.0f / DIMC) - mean * mean + 1e-5f);
      const float2 gv = ((const float2*)g)[t];
      const float2 bv = ((const float2*)bta)[t];
      ushort2 o;
      o.x = f2bf((v.x - mean) * inv * gv.x + bv.x);
      o.y = f2bf((v.y - mean) * inv * gv.y + bv.y);
      ((ushort2*)(xnb + (size_t)row * DIMC))[t] = o;
      __syncthreads();
    }
  }
  grid.sync();

  // ===== P1: qkv GEMM, 768 tiles (32 x 24), 3 per block ======================
#pragma unroll
  for (int tt = 0; tt < 3; ++tt) {
    const int tile = bid + tt * 256;
    gemm_tile<true, false, true>(xnb, wqt, nullptr, qkvb, vtb,
                                 (tile & 31) * 64, (tile >> 5) * 64,
                                 512, 1536, t, smem);
  }
  grid.sync();

  // ===== P2: fused attention, task = bid (bh = bid>>2, ntile = bid&3) ========
  {
    unsigned short* kv_lds = (unsigned short*)smem;   // 256*72
    unsigned short* p_lds = kv_lds + 256 * KSTR;      // 64*264
    const int bh = bid >> 2, b = bh >> 3, h = bh & 7;
    const int n0 = (bid & 3) * 64;

    const int dc = (t & 7) * 8;
#pragma unroll
    for (int p = 0; p < 8; ++p) {
      const int m = p * 32 + (t >> 3);
      *(s16x8*)(kv_lds + m * KSTR + dc) =
          *(const s16x8*)(qkvb + (size_t)(b * SEQ + m) * 1536 + 512 + h * 64 + dc);
    }
    s16x8 qf[2];
    const size_t qrow = (size_t)(b * SEQ + n0 + wave * 16 + fr) * 1536 + h * 64;
#pragma unroll
    for (int ks = 0; ks < 2; ++ks)
      qf[ks] = *(const s16x8*)(qkvb + qrow + ks * 32 + q4 * 8);
    __syncthreads();

    f32x4 s[16];
#pragma unroll
    for (int mt = 0; mt < 16; ++mt) s[mt] = (f32x4){0.f, 0.f, 0.f, 0.f};
#pragma unroll
    for (int ks = 0; ks < 2; ++ks)
#pragma unroll
      for (int mt = 0; mt < 16; ++mt) {
        const s16x8 kf =
            *(const s16x8*)(kv_lds + (mt * 16 + fr) * KSTR + ks * 32 + q4 * 8);
        s[mt] = __builtin_amdgcn_mfma_f32_16x16x32_bf16(qf[ks], kf, s[mt], 0, 0, 0);
      }

    float mx[4] = {-1e30f, -1e30f, -1e30f, -1e30f};
#pragma unroll
    for (int mt = 0; mt < 16; ++mt)
#pragma unroll
      for (int r = 0; r < 4; ++r) {
        s[mt][r] *= SCALEF;
        mx[r] = fmaxf(mx[r], s[mt][r]);
      }
#pragma unroll
    for (int r = 0; r < 4; ++r) {
      mx[r] = fmaxf(mx[r], __shfl_xor(mx[r], 1));
      mx[r] = fmaxf(mx[r], __shfl_xor(mx[r], 2));
      mx[r] = fmaxf(mx[r], __shfl_xor(mx[r], 4));
      mx[r] = fmaxf(mx[r], __shfl_xor(mx[r], 8));
    }
    float sum[4] = {0.f, 0.f, 0.f, 0.f};
#pragma unroll
    for (int mt = 0; mt < 16; ++mt)
#pragma unroll
      for (int r = 0; r < 4; ++r) {
        s[mt][r] = __expf(s[mt][r] - mx[r]);
        sum[r] += s[mt][r];
      }
#pragma unroll
    for (int r = 0; r < 4; ++r) {
      sum[r] += __shfl_xor(sum[r], 1);
      sum[r] += __shfl_xor(sum[r], 2);
      sum[r] += __shfl_xor(sum[r], 4);
      sum[r] += __shfl_xor(sum[r], 8);
    }
    const float invs[4] = {1.0f / sum[0], 1.0f / sum[1], 1.0f / sum[2],
                           1.0f / sum[3]};
    __syncthreads();  // all waves done reading K before V^T overwrite

    {
      const int nb = wave * 16 + q4 * 4;
#pragma unroll
      for (int mt = 0; mt < 16; ++mt)
#pragma unroll
        for (int r = 0; r < 4; ++r)
          p_lds[(nb + r) * PSTR + mt * 16 + fr] = f2bf(s[mt][r] * invs[r]);
    }
#pragma unroll
    for (int p = 0; p < 8; ++p) {
      const int idx = p * 256 + t;
      const int d = idx >> 5, c = idx & 31;
      *(s16x8*)(kv_lds + d * PSTR + c * 8) =
          *(const s16x8*)(vtb + (size_t)(bh * 64 + d) * 256 + c * 8);
    }
    __syncthreads();

#pragma unroll
    for (int p = 0; p < 8; ++p) {
      const int idx = p * 256 + t;
      const int row = idx >> 5, mc = (idx & 31) * 8;
      *(s16x8*)(attnb + (size_t)(bh * SEQ + n0 + row) * SEQ + mc) =
          *(const s16x8*)(p_lds + row * PSTR + mc);
    }

    f32x4 o[4];
#pragma unroll
    for (int dt = 0; dt < 4; ++dt) o[dt] = (f32x4){0.f, 0.f, 0.f, 0.f};
#pragma unroll
    for (int ks = 0; ks < 8; ++ks) {
      const s16x8 pf =
          *(const s16x8*)(p_lds + (wave * 16 + fr) * PSTR + ks * 32 + q4 * 8);
#pragma unroll
      for (int dt = 0; dt < 4; ++dt) {
        const s16x8 vf =
            *(const s16x8*)(kv_lds + (dt * 16 + fr) * PSTR + ks * 32 + q4 * 8);
        o[dt] = __builtin_amdgcn_mfma_f32_16x16x32_bf16(pf, vf, o[dt], 0, 0, 0);
      }
    }
#pragma unroll
    for (int dt = 0; dt < 4; ++dt)
#pragma unroll
      for (int r = 0; r < 4; ++r) {
        const int n = n0 + wave * 16 + q4 * 4 + r;
        ob[(size_t)(b * SEQ + n) * DIMC + h * 64 + dt * 16 + fr] = f2bf(o[dt][r]);
      }
  }
  grid.sync();

  // ===== P3: rpos gather + add, 16 wave-tasks per block ======================
  {
    float* aW = (float*)smem + wave * 4 * RSTRIDE;
    const int m4 = lane * 4;
    const int sm4 = m4 + ((m4 >> 6) << 3);
    const int g8 = lane >> 3, dl = lane & 7;
    const int sbase = g8 * 32 + (g8 >> 1) * 8;
    for (int it = 0; it < 4; ++it) {
      const int idx = bid * 16 + it * 4 + wave;
      const int bhalf = idx & 1;
      const int h = (idx >> 1) & 7;
      const int n = idx >> 4;
#pragma unroll
      for (int bl = 0; bl < 4; ++bl) {
        const int b = bhalf * 4 + bl;
        const ushort4 v =
            *(const ushort4*)&attnb[(size_t)((b * 8 + h) * SEQ + n) * SEQ + m4];
        float4 f;
        f.x = bf2f(v.x); f.y = bf2f(v.y); f.z = bf2f(v.z); f.w = bf2f(v.w);
        *(float4*)&aW[bl * RSTRIDE + sm4] = f;
      }
      __syncthreads();

      const int xn = n >> 4, yn = n & 15;
      float acc[4][8];
#pragma unroll
      for (int bl = 0; bl < 4; ++bl)
#pragma unroll
        for (int j = 0; j < 8; ++j) acc[bl][j] = 0.0f;
#pragma unroll 4
      for (int mm = 0; mm < 32; ++mm) {
        const int m = g8 * 32 + mm;
        const int xm = m >> 4, ym = m & 15;
        const int row = (xn - xm + 15) * 31 + (yn - ym + 15);
        const s16x8 uv =
            *(const s16x8*)(upb + (size_t)row * DIMC + h * 64 + dl * 8);
        float uf[8];
#pragma unroll
        for (int j = 0; j < 8; ++j) uf[j] = bf2f((unsigned short)uv[j]);
        float ab[4];
#pragma unroll
        for (int bl = 0; bl < 4; ++bl) ab[bl] = aW[bl * RSTRIDE + sbase + mm];
#pragma unroll
        for (int bl = 0; bl < 4; ++bl)
#pragma unroll
          for (int j = 0; j < 8; ++j) acc[bl][j] += ab[bl] * uf[j];
      }
#pragma unroll
      for (int bl = 0; bl < 4; ++bl)
#pragma unroll
        for (int j = 0; j < 8; ++j) {
          float v = acc[bl][j];
          v += __shfl_xor(v, 8);
          v += __shfl_xor(v, 16);
          v += __shfl_xor(v, 32);
          acc[bl][j] = v;
        }
      if (g8 < 4) {
        const int b = bhalf * 4 + g8;
        unsigned short* p = ob + (size_t)(b * SEQ + n) * DIMC + h * 64 + dl * 8;
        s16x8 pv = *(s16x8*)p;
        s16x8 w;
#pragma unroll
        for (int j = 0; j < 8; ++j)
          w[j] = (short)f2bf(bf2f((unsigned short)pv[j]) + acc[g8][j]);
        *(s16x8*)p = w;
      }
      __syncthreads();  // protect aW reuse next iteration
    }
  }
  grid.sync();

  // ===== P4: out-proj GEMM, 256 tiles (32 x 8), 1 per block ==================
  gemm_tile<false, true, false>(ob, wot, b_out, out, nullptr,
                                (bid & 31) * 64, (bid >> 5) * 64,
                                512, 512, t, smem);
}

extern "C" void kernel_launch(void* const* d_in, const int* in_sizes, int n_in,
                              void* d_out, int out_size, void* d_ws,
                              size_t ws_size, hipStream_t stream) {
  const float* x = (const float*)d_in[0];
  const float* ln_g = (const float*)d_in[1];
  const float* ln_b = (const float*)d_in[2];
  const float* w_qkv = (const float*)d_in[3];
  const float* up = (const float*)d_in[4];
  const float* w_out = (const float*)d_in[5];
  const float* b_out = (const float*)d_in[6];
  float* out = (float*)d_out;

  unsigned short* u = (unsigned short*)d_ws;
  unsigned short* qkvb = u;                  // 3,145,728 (V third unused)
  unsigned short* attnb = u + 3145728;       // 4,194,304
  unsigned short* xnb = u + 7340032;         // 1,048,576
  unsigned short* ob = u + 8388608;          // 1,048,576
  unsigned short* wqt = u + 9437184;         //   786,432
  unsigned short* wot = u + 10223616;        //   262,144
  unsigned short* upb = u + 10485760;        //   492,032
  unsigned short* vtb = u + 10977792;        // 1,048,576
  if (ws_size < (size_t)12026368 * sizeof(unsigned short)) return;  // ~24 MB

  void* args[] = {(void*)&x,    (void*)&ln_g, (void*)&ln_b, (void*)&w_qkv,
                  (void*)&w_out, (void*)&b_out, (void*)&up,  (void*)&out,
                  (void*)&xnb,  (void*)&wqt,  (void*)&wot,  (void*)&upb,
                  (void*)&qkvb, (void*)&vtb,  (void*)&attnb, (void*)&ob};
  hipLaunchCooperativeKernel((void*)mega_kernel, dim3(256), dim3(256),
                             args, 0, stream);
}

// Round 11
// 120.577 us; speedup vs baseline: 2.2191x; 2.2191x over previous
//
#include <hip/hip_runtime.h>
#include <math.h>

#define NB 8
#define SEQ 256
#define DIMC 512
#define NHEAD 8
#define DHEAD 64
#define SCALEF 0.125f

typedef __attribute__((ext_vector_type(8))) short s16x8;
typedef __attribute__((ext_vector_type(4))) float f32x4;

typedef __attribute__((address_space(3))) unsigned int lds_u32_t;
typedef const __attribute__((address_space(1))) unsigned int g_u32_t;
static __device__ __forceinline__ void gl_lds16(const void* gsrc, void* ldst) {
  __builtin_amdgcn_global_load_lds((g_u32_t*)gsrc, (lds_u32_t*)ldst, 16, 0, 0);
}

static __device__ __forceinline__ unsigned short f2bf(float f) {
  union { float f; unsigned u; } c; c.f = f;
  unsigned r = c.u + 0x7FFF + ((c.u >> 16) & 1);  // RNE
  return (unsigned short)(r >> 16);
}
static __device__ __forceinline__ float bf2f(unsigned short u) {
  union { unsigned u; float f; } c; c.u = ((unsigned)u) << 16;
  return c.f;
}

// ---------------- K0: fused prep: tcast(w_qkv), tcast(w_out), up->bf16, LN ---
static __device__ void tcast_body(const float* __restrict__ W,
    unsigned short* __restrict__ WT, int K, int N, int n0, int k0, int t,
    float (*tile)[65]) {
#pragma unroll
  for (int i = 0; i < 16; ++i) {
    const int idx = i * 256 + t;
    const int kl = idx >> 6, nl = idx & 63;
    tile[kl][nl] = W[(size_t)(k0 + kl) * N + n0 + nl];
  }
  __syncthreads();
#pragma unroll
  for (int i = 0; i < 16; ++i) {
    const int idx = i * 256 + t;
    const int nl = idx >> 6, kl = idx & 63;
    WT[(size_t)(n0 + nl) * K + k0 + kl] = f2bf(tile[kl][nl]);
  }
}

__global__ __launch_bounds__(256) void prep_kernel(const float* __restrict__ x,
    const float* __restrict__ g, const float* __restrict__ bta,
    const float* __restrict__ w_qkv, const float* __restrict__ w_out,
    const float* __restrict__ up, unsigned short* __restrict__ xnb,
    unsigned short* __restrict__ wqt, unsigned short* __restrict__ wot,
    unsigned short* __restrict__ upb) {
  __shared__ float tile[64][65];
  __shared__ float sh_s[4], sh_q[4];
  const int t = threadIdx.x;
  const int bid = blockIdx.x;
  if (bid < 192) {
    tcast_body(w_qkv, wqt, 512, 1536, (bid % 24) * 64, (bid / 24) * 64, t, tile);
  } else if (bid < 256) {
    const int b2 = bid - 192;
    tcast_body(w_out, wot, 512, 512, (b2 % 8) * 64, (b2 / 8) * 64, t, tile);
  } else if (bid < 497) {
    const int base = (bid - 256) * 2048 + t * 4;
#pragma unroll
    for (int it = 0; it < 2; ++it) {
      const int i = base + it * 1024;
      if (i < 492032) {
        const float4 v = *(const float4*)&up[i];
        ushort4 w;
        w.x = f2bf(v.x); w.y = f2bf(v.y); w.z = f2bf(v.z); w.w = f2bf(v.w);
        *(ushort4*)&upb[i] = w;
      }
    }
  } else {
    const int row = bid - 497;
    const float2 v = ((const float2*)(x + (size_t)row * DIMC))[t];
    float s = v.x + v.y;
    float q = v.x * v.x + v.y * v.y;
#pragma unroll
    for (int off = 32; off > 0; off >>= 1) {
      s += __shfl_down(s, off);
      q += __shfl_down(q, off);
    }
    const int wave = t >> 6, lane = t & 63;
    if (lane == 0) { sh_s[wave] = s; sh_q[wave] = q; }
    __syncthreads();
    const float fs = sh_s[0] + sh_s[1] + sh_s[2] + sh_s[3];
    const float fq = sh_q[0] + sh_q[1] + sh_q[2] + sh_q[3];
    const float mean = fs * (1.0f / DIMC);
    const float inv = rsqrtf(fq * (1.0f / DIMC) - mean * mean + 1e-5f);
    const float2 gv = ((const float2*)g)[t];
    const float2 bv = ((const float2*)bta)[t];
    ushort2 o;
    o.x = f2bf((v.x - mean) * inv * gv.x + bv.x);
    o.y = f2bf((v.y - mean) * inv * gv.y + bv.y);
    ((ushort2*)(xnb + (size_t)row * DIMC))[t] = o;
  }
}

// ---------------- bf16 MFMA GEMM: C = A(MxK) @ BT(NxK)^T (+bias) -------------
// VSPLIT (qkv only): output cols >=1024 (the V third) go transposed to
// vtb[(b*8+h)*64 + d][m] instead of row-major C (block-uniform branch).
template <int BM, int BN, bool BIAS, bool OUTBF, bool VSPLIT>
__global__ __launch_bounds__(256) void mfma_gemm_bt(
    const unsigned short* __restrict__ A, const unsigned short* __restrict__ BT,
    const float* __restrict__ bias, void* __restrict__ Cv,
    unsigned short* __restrict__ vtb, int M, int K, int N) {
  constexpr int TR = BM / 32;
  constexpr int TC = BN / 32;
  __shared__ unsigned short As[BM * 32];
  __shared__ unsigned short Bs[BN * 32];
  const int t = threadIdx.x;
  const int wave = t >> 6, lane = t & 63;
  const int wr = wave >> 1, wc = wave & 1;
  const int bm = blockIdx.x * BM, bn = blockIdx.y * BN;

  f32x4 acc[TR][TC] = {};

  const int fr = lane & 15, q4 = lane >> 4;
  const int kBlocks = K >> 5;
  for (int kb = 0; kb < kBlocks; ++kb) {
    const int k0 = kb << 5;
    __syncthreads();
#pragma unroll
    for (int c = 0; c < (BM * 4 + 255) / 256; ++c) {
      const int p = c * 256 + t;
      if (BM * 4 % 256 == 0 || p < BM * 4) {
        const int row = p >> 2;
        const int jl = (p & 3) ^ ((row >> 1) & 3);
        gl_lds16(A + (size_t)(bm + row) * K + k0 + jl * 8,
                 As + (size_t)(c * 256 + wave * 64) * 8);
      }
    }
#pragma unroll
    for (int c = 0; c < (BN * 4 + 255) / 256; ++c) {
      const int p = c * 256 + t;
      if (BN * 4 % 256 == 0 || p < BN * 4) {
        const int row = p >> 2;
        const int jl = (p & 3) ^ ((row >> 1) & 3);
        gl_lds16(BT + (size_t)(bn + row) * K + k0 + jl * 8,
                 Bs + (size_t)(c * 256 + wave * 64) * 8);
      }
    }
    __syncthreads();
    s16x8 af[TR], bfr[TC];
#pragma unroll
    for (int i = 0; i < TR; ++i) {
      const int row = wr * (BM / 2) + i * 16 + fr;
      const int jp = q4 ^ ((row >> 1) & 3);
      af[i] = *(const s16x8*)(As + row * 32 + jp * 8);
    }
#pragma unroll
    for (int j = 0; j < TC; ++j) {
      const int row = wc * (BN / 2) + j * 16 + fr;
      const int jp = q4 ^ ((row >> 1) & 3);
      bfr[j] = *(const s16x8*)(Bs + row * 32 + jp * 8);
    }
#pragma unroll
    for (int i = 0; i < TR; ++i)
#pragma unroll
      for (int j = 0; j < TC; ++j)
        acc[i][j] = __builtin_amdgcn_mfma_f32_16x16x32_bf16(af[i], bfr[j],
                                                            acc[i][j], 0, 0, 0);
  }
  if (VSPLIT && bn >= 1024) {
#pragma unroll
    for (int i = 0; i < TR; ++i) {
#pragma unroll
      for (int j = 0; j < TC; ++j) {
        const int hc = bn - 1024 + wc * (BN / 2) + j * 16 + fr;
        const int h = hc >> 6, d = hc & 63;
#pragma unroll
        for (int r = 0; r < 4; ++r) {
          const int row = bm + wr * (BM / 2) + i * 16 + q4 * 4 + r;
          const int b = row >> 8, m = row & 255;
          vtb[(size_t)((b * 8 + h) * 64 + d) * 256 + m] = f2bf(acc[i][j][r]);
        }
      }
    }
    return;
  }
#pragma unroll
  for (int i = 0; i < TR; ++i) {
#pragma unroll
    for (int j = 0; j < TC; ++j) {
      const int col = bn + wc * (BN / 2) + j * 16 + fr;
      const float bv = BIAS ? bias[col] : 0.0f;
#pragma unroll
      for (int r = 0; r < 4; ++r) {
        const int row = bm + wr * (BM / 2) + i * 16 + q4 * 4 + r;
        if constexpr (OUTBF) {
          ((unsigned short*)Cv)[(size_t)row * N + col] = f2bf(acc[i][j][r] + bv);
        } else {
          ((float*)Cv)[(size_t)row * N + col] = acc[i][j][r] + bv;
        }
      }
    }
  }
}

// ---------------- K3: fused QK^T -> softmax -> AV, 128 thr / 32 n-rows -------
// grid (8 ntiles, 64 bh). V^T comes pre-transposed from the qkv GEMM (vtb).
#define PSTR 264
#define KSTR 72
__global__ __launch_bounds__(128) void fused_attn_kernel(
    const unsigned short* __restrict__ qkvb, const unsigned short* __restrict__ vtb,
    unsigned short* __restrict__ attnb, unsigned short* __restrict__ oav) {
  __shared__ unsigned short kv_lds[256 * KSTR];  // K stage, then V^T stage
  __shared__ unsigned short p_lds[32 * PSTR];
  const int bh = blockIdx.y, b = bh >> 3, h = bh & 7;
  const int n0 = blockIdx.x * 32;
  const int t = threadIdx.x, wave = t >> 6, lane = t & 63;
  const int fr = lane & 15, q4 = lane >> 4;

  // stage K[m][d]: 256 rows x 8 chunks of 16B = 2048 chunks / 128 thr
#pragma unroll
  for (int p = 0; p < 16; ++p) {
    const int chunk = p * 128 + t;
    const int m = chunk >> 3, c = chunk & 7;
    *(s16x8*)(kv_lds + m * KSTR + c * 8) =
        *(const s16x8*)(qkvb + (size_t)(b * SEQ + m) * 1536 + 512 + h * 64 + c * 8);
  }
  s16x8 qf[2];
  {
    const size_t qrow = (size_t)(b * SEQ + n0 + wave * 16 + fr) * 1536 + h * 64;
#pragma unroll
    for (int ks = 0; ks < 2; ++ks)
      qf[ks] = *(const s16x8*)(qkvb + qrow + ks * 32 + q4 * 8);
  }
  __syncthreads();

  f32x4 s[16];
#pragma unroll
  for (int mt = 0; mt < 16; ++mt) s[mt] = (f32x4){0.f, 0.f, 0.f, 0.f};
#pragma unroll
  for (int ks = 0; ks < 2; ++ks)
#pragma unroll
    for (int mt = 0; mt < 16; ++mt) {
      const s16x8 kf =
          *(const s16x8*)(kv_lds + (mt * 16 + fr) * KSTR + ks * 32 + q4 * 8);
      s[mt] = __builtin_amdgcn_mfma_f32_16x16x32_bf16(qf[ks], kf, s[mt], 0, 0, 0);
    }

  float mx[4] = {-1e30f, -1e30f, -1e30f, -1e30f};
#pragma unroll
  for (int mt = 0; mt < 16; ++mt)
#pragma unroll
    for (int r = 0; r < 4; ++r) {
      s[mt][r] *= SCALEF;
      mx[r] = fmaxf(mx[r], s[mt][r]);
    }
#pragma unroll
  for (int r = 0; r < 4; ++r) {
    mx[r] = fmaxf(mx[r], __shfl_xor(mx[r], 1));
    mx[r] = fmaxf(mx[r], __shfl_xor(mx[r], 2));
    mx[r] = fmaxf(mx[r], __shfl_xor(mx[r], 4));
    mx[r] = fmaxf(mx[r], __shfl_xor(mx[r], 8));
  }
  float sum[4] = {0.f, 0.f, 0.f, 0.f};
#pragma unroll
  for (int mt = 0; mt < 16; ++mt)
#pragma unroll
    for (int r = 0; r < 4; ++r) {
      s[mt][r] = __expf(s[mt][r] - mx[r]);
      sum[r] += s[mt][r];
    }
#pragma unroll
  for (int r = 0; r < 4; ++r) {
    sum[r] += __shfl_xor(sum[r], 1);
    sum[r] += __shfl_xor(sum[r], 2);
    sum[r] += __shfl_xor(sum[r], 4);
    sum[r] += __shfl_xor(sum[r], 8);
  }
  const float invs[4] = {1.0f / sum[0], 1.0f / sum[1], 1.0f / sum[2],
                         1.0f / sum[3]};

  __syncthreads();  // waves done with K before V^T overwrites kv_lds

  // P -> p_lds (bf16), V^T -> kv_lds (vector b128, 2048 chunks / 128 thr)
  {
    const int nb = wave * 16 + q4 * 4;
#pragma unroll
    for (int mt = 0; mt < 16; ++mt)
#pragma unroll
      for (int r = 0; r < 4; ++r)
        p_lds[(nb + r) * PSTR + mt * 16 + fr] = f2bf(s[mt][r] * invs[r]);
  }
#pragma unroll
  for (int p = 0; p < 16; ++p) {
    const int idx = p * 128 + t;
    const int d = idx >> 5, c = idx & 31;
    *(s16x8*)(kv_lds + d * PSTR + c * 8) =
        *(const s16x8*)(vtb + (size_t)(bh * 64 + d) * 256 + c * 8);
  }
  __syncthreads();

  // copy P -> global attn (bf16) for the rpos kernel
#pragma unroll
  for (int p = 0; p < 8; ++p) {
    const int idx = p * 128 + t;
    const int row = idx >> 5, mc = (idx & 31) * 8;
    *(s16x8*)(attnb + (size_t)(bh * SEQ + n0 + row) * SEQ + mc) =
        *(const s16x8*)(p_lds + row * PSTR + mc);
  }

  f32x4 o[4];
#pragma unroll
  for (int dt = 0; dt < 4; ++dt) o[dt] = (f32x4){0.f, 0.f, 0.f, 0.f};
#pragma unroll
  for (int ks = 0; ks < 8; ++ks) {
    const s16x8 pf =
        *(const s16x8*)(p_lds + (wave * 16 + fr) * PSTR + ks * 32 + q4 * 8);
#pragma unroll
    for (int dt = 0; dt < 4; ++dt) {
      const s16x8 vf =
          *(const s16x8*)(kv_lds + (dt * 16 + fr) * PSTR + ks * 32 + q4 * 8);
      o[dt] = __builtin_amdgcn_mfma_f32_16x16x32_bf16(pf, vf, o[dt], 0, 0, 0);
    }
  }
#pragma unroll
  for (int dt = 0; dt < 4; ++dt)
#pragma unroll
    for (int r = 0; r < 4; ++r) {
      const int n = n0 + wave * 16 + q4 * 4 + r;
      oav[(size_t)(b * SEQ + n) * DIMC + h * 64 + dt * 16 + fr] = f2bf(o[dt][r]);
    }
}

// ---------------- K4: rpos gather + o_av add, wave per (n,h,bhalf) -----------
#define RSTRIDE 280
__global__ __launch_bounds__(256) void rpos_kernel(
    const unsigned short* __restrict__ attnb, const unsigned short* __restrict__ upb,
    unsigned short* __restrict__ ob) {
  __shared__ float aS[4][4 * RSTRIDE];
  const int t = threadIdx.x;
  const int wave = t >> 6, lane = t & 63;
  const int g = lane >> 4, dg = lane & 15;
  const int idx = blockIdx.x * 4 + wave;   // 4096 tasks
  const int bhalf = idx & 1;
  const int h = (idx >> 1) & 7;
  const int n = idx >> 4;
  float* aW = aS[wave];

  const int m4 = lane * 4;
  const int sm4 = m4 + ((m4 >> 6) << 3);
#pragma unroll
  for (int bl = 0; bl < 4; ++bl) {
    const int b = bhalf * 4 + bl;
    const ushort4 v =
        *(const ushort4*)&attnb[(size_t)((b * 8 + h) * SEQ + n) * SEQ + m4];
    float4 f;
    f.x = bf2f(v.x); f.y = bf2f(v.y); f.z = bf2f(v.z); f.w = bf2f(v.w);
    *(float4*)&aW[bl * RSTRIDE + sm4] = f;
  }
  __syncthreads();

  const int xn = n >> 4, yn = n & 15;
  float acc[4][4];
#pragma unroll
  for (int bl = 0; bl < 4; ++bl)
#pragma unroll
    for (int j = 0; j < 4; ++j) acc[bl][j] = 0.0f;

  const int mbase = g * 64;
  const int sbase = g * 72;
#pragma unroll 4
  for (int mm = 0; mm < 64; ++mm) {
    const int m = mbase + mm;
    const int xm = m >> 4, ym = m & 15;
    const int row = (xn - xm + 15) * 31 + (yn - ym + 15);
    const ushort4 uu = *(const ushort4*)&upb[(size_t)row * DIMC + h * 64 + dg * 4];
    const float ux = bf2f(uu.x), uy = bf2f(uu.y), uz = bf2f(uu.z), uw = bf2f(uu.w);
    float ab[4];
#pragma unroll
    for (int bl = 0; bl < 4; ++bl) ab[bl] = aW[bl * RSTRIDE + sbase + mm];
#pragma unroll
    for (int bl = 0; bl < 4; ++bl) {
      acc[bl][0] += ab[bl] * ux;
      acc[bl][1] += ab[bl] * uy;
      acc[bl][2] += ab[bl] * uz;
      acc[bl][3] += ab[bl] * uw;
    }
  }
#pragma unroll
  for (int bl = 0; bl < 4; ++bl)
#pragma unroll
    for (int j = 0; j < 4; ++j) {
      float v = acc[bl][j];
      v += __shfl_xor(v, 16);
      v += __shfl_xor(v, 32);
      acc[bl][j] = v;
    }
  {
    const int b = bhalf * 4 + g;
    const size_t base = (size_t)(b * SEQ + n) * DIMC + h * 64 + dg * 4;
    ushort4 pv = *(ushort4*)&ob[base];
    ushort4 w;
    w.x = f2bf(bf2f(pv.x) + acc[g][0]);
    w.y = f2bf(bf2f(pv.y) + acc[g][1]);
    w.z = f2bf(bf2f(pv.z) + acc[g][2]);
    w.w = f2bf(bf2f(pv.w) + acc[g][3]);
    *(ushort4*)&ob[base] = w;
  }
}

extern "C" void kernel_launch(void* const* d_in, const int* in_sizes, int n_in,
                              void* d_out, int out_size, void* d_ws,
                              size_t ws_size, hipStream_t stream) {
  const float* x = (const float*)d_in[0];
  const float* ln_g = (const float*)d_in[1];
  const float* ln_b = (const float*)d_in[2];
  const float* w_qkv = (const float*)d_in[3];
  const float* up = (const float*)d_in[4];
  const float* w_out = (const float*)d_in[5];
  const float* b_out = (const float*)d_in[6];
  float* out = (float*)d_out;

  unsigned short* u = (unsigned short*)d_ws;
  unsigned short* qkvb = u;                  // 3,145,728 (V third unused)
  unsigned short* attnb = u + 3145728;       // 4,194,304
  unsigned short* xnb = u + 7340032;         // 1,048,576
  unsigned short* ob = u + 8388608;          // 1,048,576
  unsigned short* wqt = u + 9437184;         //   786,432
  unsigned short* wot = u + 10223616;        //   262,144
  unsigned short* upb = u + 10485760;        //   492,032
  unsigned short* vtb = u + 10977792;        // 1,048,576
  if (ws_size < (size_t)12026368 * sizeof(unsigned short)) return;  // ~24 MB

  prep_kernel<<<2545, 256, 0, stream>>>(x, ln_g, ln_b, w_qkv, w_out, up,
                                        xnb, wqt, wot, upb);
  mfma_gemm_bt<64, 64, false, true, true>
      <<<dim3(32, 24), 256, 0, stream>>>(xnb, wqt, nullptr, qkvb, vtb,
                                         2048, 512, 1536);
  fused_attn_kernel<<<dim3(8, 64), 128, 0, stream>>>(qkvb, vtb, attnb, ob);
  rpos_kernel<<<1024, 256, 0, stream>>>(attnb, upb, ob);
  mfma_gemm_bt<64, 32, true, false, false>
      <<<dim3(32, 16), 256, 0, stream>>>(ob, wot, b_out, out, nullptr,
                                         2048, 512, 512);
}

// Round 12
// 112.465 us; speedup vs baseline: 2.3791x; 1.0721x over previous
//
#include <hip/hip_runtime.h>
#include <math.h>

#define NB 8
#define SEQ 256
#define DIMC 512
#define NHEAD 8
#define DHEAD 64
#define SCALEF 0.125f

typedef __attribute__((ext_vector_type(8))) short s16x8;
typedef __attribute__((ext_vector_type(4))) float f32x4;

typedef __attribute__((address_space(3))) unsigned int lds_u32_t;
typedef const __attribute__((address_space(1))) unsigned int g_u32_t;
static __device__ __forceinline__ void gl_lds16(const void* gsrc, void* ldst) {
  __builtin_amdgcn_global_load_lds((g_u32_t*)gsrc, (lds_u32_t*)ldst, 16, 0, 0);
}

static __device__ __forceinline__ unsigned short f2bf(float f) {
  union { float f; unsigned u; } c; c.f = f;
  unsigned r = c.u + 0x7FFF + ((c.u >> 16) & 1);  // RNE
  return (unsigned short)(r >> 16);
}
static __device__ __forceinline__ float bf2f(unsigned short u) {
  union { unsigned u; float f; } c; c.u = ((unsigned)u) << 16;
  return c.f;
}

// ---------------- K0: fused prep: tcast(w_qkv), tcast(w_out), up->bf16, LN ---
static __device__ void tcast_body(const float* __restrict__ W,
    unsigned short* __restrict__ WT, int K, int N, int n0, int k0, int t,
    float (*tile)[65]) {
#pragma unroll
  for (int i = 0; i < 16; ++i) {
    const int idx = i * 256 + t;
    const int kl = idx >> 6, nl = idx & 63;
    tile[kl][nl] = W[(size_t)(k0 + kl) * N + n0 + nl];
  }
  __syncthreads();
#pragma unroll
  for (int i = 0; i < 16; ++i) {
    const int idx = i * 256 + t;
    const int nl = idx >> 6, kl = idx & 63;
    WT[(size_t)(n0 + nl) * K + k0 + kl] = f2bf(tile[kl][nl]);
  }
}

__global__ __launch_bounds__(256) void prep_kernel(const float* __restrict__ x,
    const float* __restrict__ g, const float* __restrict__ bta,
    const float* __restrict__ w_qkv, const float* __restrict__ w_out,
    const float* __restrict__ up, unsigned short* __restrict__ xnb,
    unsigned short* __restrict__ wqt, unsigned short* __restrict__ wot,
    unsigned short* __restrict__ upb) {
  __shared__ float tile[64][65];
  __shared__ float sh_s[4], sh_q[4];
  const int t = threadIdx.x;
  const int bid = blockIdx.x;
  if (bid < 192) {
    tcast_body(w_qkv, wqt, 512, 1536, (bid % 24) * 64, (bid / 24) * 64, t, tile);
  } else if (bid < 256) {
    const int b2 = bid - 192;
    tcast_body(w_out, wot, 512, 512, (b2 % 8) * 64, (b2 / 8) * 64, t, tile);
  } else if (bid < 497) {
    const int base = (bid - 256) * 2048 + t * 4;
#pragma unroll
    for (int it = 0; it < 2; ++it) {
      const int i = base + it * 1024;
      if (i < 492032) {
        const float4 v = *(const float4*)&up[i];
        ushort4 w;
        w.x = f2bf(v.x); w.y = f2bf(v.y); w.z = f2bf(v.z); w.w = f2bf(v.w);
        *(ushort4*)&upb[i] = w;
      }
    }
  } else {
    const int row = bid - 497;
    const float2 v = ((const float2*)(x + (size_t)row * DIMC))[t];
    float s = v.x + v.y;
    float q = v.x * v.x + v.y * v.y;
#pragma unroll
    for (int off = 32; off > 0; off >>= 1) {
      s += __shfl_down(s, off);
      q += __shfl_down(q, off);
    }
    const int wave = t >> 6, lane = t & 63;
    if (lane == 0) { sh_s[wave] = s; sh_q[wave] = q; }
    __syncthreads();
    const float fs = sh_s[0] + sh_s[1] + sh_s[2] + sh_s[3];
    const float fq = sh_q[0] + sh_q[1] + sh_q[2] + sh_q[3];
    const float mean = fs * (1.0f / DIMC);
    const float inv = rsqrtf(fq * (1.0f / DIMC) - mean * mean + 1e-5f);
    const float2 gv = ((const float2*)g)[t];
    const float2 bv = ((const float2*)bta)[t];
    ushort2 o;
    o.x = f2bf((v.x - mean) * inv * gv.x + bv.x);
    o.y = f2bf((v.y - mean) * inv * gv.y + bv.y);
    ((ushort2*)(xnb + (size_t)row * DIMC))[t] = o;
  }
}

// ---------------- bf16 MFMA GEMM: C = A(MxK) @ BT(NxK)^T (+bias) -------------
template <int BM, int BN, bool BIAS, bool OUTBF, bool VSPLIT>
__global__ __launch_bounds__(256) void mfma_gemm_bt(
    const unsigned short* __restrict__ A, const unsigned short* __restrict__ BT,
    const float* __restrict__ bias, void* __restrict__ Cv,
    unsigned short* __restrict__ vtb, int M, int K, int N) {
  constexpr int TR = BM / 32;
  constexpr int TC = BN / 32;
  __shared__ unsigned short As[BM * 32];
  __shared__ unsigned short Bs[BN * 32];
  const int t = threadIdx.x;
  const int wave = t >> 6, lane = t & 63;
  const int wr = wave >> 1, wc = wave & 1;
  const int bm = blockIdx.x * BM, bn = blockIdx.y * BN;

  f32x4 acc[TR][TC] = {};

  const int fr = lane & 15, q4 = lane >> 4;
  const int kBlocks = K >> 5;
  for (int kb = 0; kb < kBlocks; ++kb) {
    const int k0 = kb << 5;
    __syncthreads();
#pragma unroll
    for (int c = 0; c < (BM * 4 + 255) / 256; ++c) {
      const int p = c * 256 + t;
      if (BM * 4 % 256 == 0 || p < BM * 4) {
        const int row = p >> 2;
        const int jl = (p & 3) ^ ((row >> 1) & 3);
        gl_lds16(A + (size_t)(bm + row) * K + k0 + jl * 8,
                 As + (size_t)(c * 256 + wave * 64) * 8);
      }
    }
#pragma unroll
    for (int c = 0; c < (BN * 4 + 255) / 256; ++c) {
      const int p = c * 256 + t;
      if (BN * 4 % 256 == 0 || p < BN * 4) {
        const int row = p >> 2;
        const int jl = (p & 3) ^ ((row >> 1) & 3);
        gl_lds16(BT + (size_t)(bn + row) * K + k0 + jl * 8,
                 Bs + (size_t)(c * 256 + wave * 64) * 8);
      }
    }
    __syncthreads();
    s16x8 af[TR], bfr[TC];
#pragma unroll
    for (int i = 0; i < TR; ++i) {
      const int row = wr * (BM / 2) + i * 16 + fr;
      const int jp = q4 ^ ((row >> 1) & 3);
      af[i] = *(const s16x8*)(As + row * 32 + jp * 8);
    }
#pragma unroll
    for (int j = 0; j < TC; ++j) {
      const int row = wc * (BN / 2) + j * 16 + fr;
      const int jp = q4 ^ ((row >> 1) & 3);
      bfr[j] = *(const s16x8*)(Bs + row * 32 + jp * 8);
    }
#pragma unroll
    for (int i = 0; i < TR; ++i)
#pragma unroll
      for (int j = 0; j < TC; ++j)
        acc[i][j] = __builtin_amdgcn_mfma_f32_16x16x32_bf16(af[i], bfr[j],
                                                            acc[i][j], 0, 0, 0);
  }
  if (VSPLIT && bn >= 1024) {
#pragma unroll
    for (int i = 0; i < TR; ++i) {
#pragma unroll
      for (int j = 0; j < TC; ++j) {
        const int hc = bn - 1024 + wc * (BN / 2) + j * 16 + fr;
        const int h = hc >> 6, d = hc & 63;
#pragma unroll
        for (int r = 0; r < 4; ++r) {
          const int row = bm + wr * (BM / 2) + i * 16 + q4 * 4 + r;
          const int b = row >> 8, m = row & 255;
          vtb[(size_t)((b * 8 + h) * 64 + d) * 256 + m] = f2bf(acc[i][j][r]);
        }
      }
    }
    return;
  }
#pragma unroll
  for (int i = 0; i < TR; ++i) {
#pragma unroll
    for (int j = 0; j < TC; ++j) {
      const int col = bn + wc * (BN / 2) + j * 16 + fr;
      const float bv = BIAS ? bias[col] : 0.0f;
#pragma unroll
      for (int r = 0; r < 4; ++r) {
        const int row = bm + wr * (BM / 2) + i * 16 + q4 * 4 + r;
        if constexpr (OUTBF) {
          ((unsigned short*)Cv)[(size_t)row * N + col] = f2bf(acc[i][j][r] + bv);
        } else {
          ((float*)Cv)[(size_t)row * N + col] = acc[i][j][r] + bv;
        }
      }
    }
  }
}

// ---------------- K3: fused QK^T -> softmax -> AV, 128 thr / 32 n-rows -------
#define PSTR 264
#define KSTR 72
__global__ __launch_bounds__(128) void fused_attn_kernel(
    const unsigned short* __restrict__ qkvb, const unsigned short* __restrict__ vtb,
    unsigned short* __restrict__ attnb, unsigned short* __restrict__ oav) {
  __shared__ unsigned short kv_lds[256 * KSTR];  // K stage, then V^T stage
  __shared__ unsigned short p_lds[32 * PSTR];
  const int bh = blockIdx.y, b = bh >> 3, h = bh & 7;
  const int n0 = blockIdx.x * 32;
  const int t = threadIdx.x, wave = t >> 6, lane = t & 63;
  const int fr = lane & 15, q4 = lane >> 4;

#pragma unroll
  for (int p = 0; p < 16; ++p) {
    const int chunk = p * 128 + t;
    const int m = chunk >> 3, c = chunk & 7;
    *(s16x8*)(kv_lds + m * KSTR + c * 8) =
        *(const s16x8*)(qkvb + (size_t)(b * SEQ + m) * 1536 + 512 + h * 64 + c * 8);
  }
  s16x8 qf[2];
  {
    const size_t qrow = (size_t)(b * SEQ + n0 + wave * 16 + fr) * 1536 + h * 64;
#pragma unroll
    for (int ks = 0; ks < 2; ++ks)
      qf[ks] = *(const s16x8*)(qkvb + qrow + ks * 32 + q4 * 8);
  }
  __syncthreads();

  f32x4 s[16];
#pragma unroll
  for (int mt = 0; mt < 16; ++mt) s[mt] = (f32x4){0.f, 0.f, 0.f, 0.f};
#pragma unroll
  for (int ks = 0; ks < 2; ++ks)
#pragma unroll
    for (int mt = 0; mt < 16; ++mt) {
      const s16x8 kf =
          *(const s16x8*)(kv_lds + (mt * 16 + fr) * KSTR + ks * 32 + q4 * 8);
      s[mt] = __builtin_amdgcn_mfma_f32_16x16x32_bf16(qf[ks], kf, s[mt], 0, 0, 0);
    }

  float mx[4] = {-1e30f, -1e30f, -1e30f, -1e30f};
#pragma unroll
  for (int mt = 0; mt < 16; ++mt)
#pragma unroll
    for (int r = 0; r < 4; ++r) {
      s[mt][r] *= SCALEF;
      mx[r] = fmaxf(mx[r], s[mt][r]);
    }
#pragma unroll
  for (int r = 0; r < 4; ++r) {
    mx[r] = fmaxf(mx[r], __shfl_xor(mx[r], 1));
    mx[r] = fmaxf(mx[r], __shfl_xor(mx[r], 2));
    mx[r] = fmaxf(mx[r], __shfl_xor(mx[r], 4));
    mx[r] = fmaxf(mx[r], __shfl_xor(mx[r], 8));
  }
  float sum[4] = {0.f, 0.f, 0.f, 0.f};
#pragma unroll
  for (int mt = 0; mt < 16; ++mt)
#pragma unroll
    for (int r = 0; r < 4; ++r) {
      s[mt][r] = __expf(s[mt][r] - mx[r]);
      sum[r] += s[mt][r];
    }
#pragma unroll
  for (int r = 0; r < 4; ++r) {
    sum[r] += __shfl_xor(sum[r], 1);
    sum[r] += __shfl_xor(sum[r], 2);
    sum[r] += __shfl_xor(sum[r], 4);
    sum[r] += __shfl_xor(sum[r], 8);
  }
  const float invs[4] = {1.0f / sum[0], 1.0f / sum[1], 1.0f / sum[2],
                         1.0f / sum[3]};

  __syncthreads();  // waves done with K before V^T overwrites kv_lds

  {
    const int nb = wave * 16 + q4 * 4;
#pragma unroll
    for (int mt = 0; mt < 16; ++mt)
#pragma unroll
      for (int r = 0; r < 4; ++r)
        p_lds[(nb + r) * PSTR + mt * 16 + fr] = f2bf(s[mt][r] * invs[r]);
  }
#pragma unroll
  for (int p = 0; p < 16; ++p) {
    const int idx = p * 128 + t;
    const int d = idx >> 5, c = idx & 31;
    *(s16x8*)(kv_lds + d * PSTR + c * 8) =
        *(const s16x8*)(vtb + (size_t)(bh * 64 + d) * 256 + c * 8);
  }
  __syncthreads();

#pragma unroll
  for (int p = 0; p < 8; ++p) {
    const int idx = p * 128 + t;
    const int row = idx >> 5, mc = (idx & 31) * 8;
    *(s16x8*)(attnb + (size_t)(bh * SEQ + n0 + row) * SEQ + mc) =
        *(const s16x8*)(p_lds + row * PSTR + mc);
  }

  f32x4 o[4];
#pragma unroll
  for (int dt = 0; dt < 4; ++dt) o[dt] = (f32x4){0.f, 0.f, 0.f, 0.f};
#pragma unroll
  for (int ks = 0; ks < 8; ++ks) {
    const s16x8 pf =
        *(const s16x8*)(p_lds + (wave * 16 + fr) * PSTR + ks * 32 + q4 * 8);
#pragma unroll
    for (int dt = 0; dt < 4; ++dt) {
      const s16x8 vf =
          *(const s16x8*)(kv_lds + (dt * 16 + fr) * PSTR + ks * 32 + q4 * 8);
      o[dt] = __builtin_amdgcn_mfma_f32_16x16x32_bf16(pf, vf, o[dt], 0, 0, 0);
    }
  }
#pragma unroll
  for (int dt = 0; dt < 4; ++dt)
#pragma unroll
    for (int r = 0; r < 4; ++r) {
      const int n = n0 + wave * 16 + q4 * 4 + r;
      oav[(size_t)(b * SEQ + n) * DIMC + h * 64 + dt * 16 + fr] = f2bf(o[dt][r]);
    }
}

// ---------------- K4: rpos as MFMA GEMM, block per (n,h) ---------------------
// out_rpos[b][d] = sum_m attn[b,h,n,m] * up[idx(n,m)][h*64+d]
//   A = attn rows (M=8 pad 16, K=256 m), B = gathered upT (K=256 m, N=64 d).
// upT staged [d][m] with chunk-XOR swizzle (m-chunk ^ (d>>3)) -> both the
// transpose-write and the B-frag b128 reads are <=2-way bank patterns (free).
#define USTR 264   // upT row stride in bf16 (16B-aligned rows)
#define ASTR2 264
__global__ __launch_bounds__(256) void rpos_kernel(
    const unsigned short* __restrict__ attnb, const unsigned short* __restrict__ upb,
    unsigned short* __restrict__ ob) {
  __shared__ unsigned short upT[64 * USTR];   // 33,792 B
  __shared__ unsigned short aS[16 * ASTR2];   //  8,448 B (rows 8-15 unused)
  const int t = threadIdx.x, wave = t >> 6, lane = t & 63;
  const int fr = lane & 15, q4 = lane >> 4;
  const int task = blockIdx.x;                // 2048 = 256 n x 8 h
  const int n = task >> 3, h = task & 7;
  const int xn = n >> 4, yn = n & 15;

  // stage attn A rows: 8 b x 256 m (one s16x8 per thread)
  {
    const int b = t >> 5, mc = (t & 31) * 8;
    *(s16x8*)(aS + b * ASTR2 + mc) =
        *(const s16x8*)(attnb + (size_t)((b * 8 + h) * SEQ + n) * SEQ + mc);
  }
  // gather + transpose up rows into upT: 2048 16B-chunks / 256 thr
#pragma unroll
  for (int i = 0; i < 8; ++i) {
    const int chunk = i * 256 + t;
    const int m = chunk >> 3;                 // source m row
    const int g8 = chunk & 7;                 // d-octet
    const int xm = m >> 4, ym = m & 15;
    const int row = (xn - xm + 15) * 31 + (yn - ym + 15);
    const s16x8 v = *(const s16x8*)(upb + (size_t)row * DIMC + h * 64 + g8 * 8);
    const int mc_phys = ((m >> 3) ^ g8) * 8 + (m & 7);  // XOR swizzle on m-chunk
#pragma unroll
    for (int j = 0; j < 8; ++j)
      upT[(g8 * 8 + j) * USTR + mc_phys] = (unsigned short)v[j];
  }
  __syncthreads();

  // D[M=16 b-pad][N=16 d] per wave; K=256 in 8 MFMA steps
  f32x4 acc = (f32x4){0.f, 0.f, 0.f, 0.f};
  const int d = wave * 16 + fr;               // B-frag N-row
#pragma unroll
  for (int ks = 0; ks < 8; ++ks) {
    const s16x8 af = *(const s16x8*)(aS + fr * ASTR2 + ks * 32 + q4 * 8);
    const int c_phys = (ks * 4 + q4) ^ (d >> 3);
    const s16x8 bf = *(const s16x8*)(upT + d * USTR + c_phys * 8);
    acc = __builtin_amdgcn_mfma_f32_16x16x32_bf16(af, bf, acc, 0, 0, 0);
  }
  // C-layout: col = fr = d-within-tile, row = q4*4+r = b (valid b < 8)
  if (q4 < 2) {
#pragma unroll
    for (int r = 0; r < 4; ++r) {
      const int b = q4 * 4 + r;
      unsigned short* p = ob + (size_t)(b * SEQ + n) * DIMC + h * 64 + d;
      *p = f2bf(bf2f(*p) + acc[r]);
    }
  }
}

extern "C" void kernel_launch(void* const* d_in, const int* in_sizes, int n_in,
                              void* d_out, int out_size, void* d_ws,
                              size_t ws_size, hipStream_t stream) {
  const float* x = (const float*)d_in[0];
  const float* ln_g = (const float*)d_in[1];
  const float* ln_b = (const float*)d_in[2];
  const float* w_qkv = (const float*)d_in[3];
  const float* up = (const float*)d_in[4];
  const float* w_out = (const float*)d_in[5];
  const float* b_out = (const float*)d_in[6];
  float* out = (float*)d_out;

  unsigned short* u = (unsigned short*)d_ws;
  unsigned short* qkvb = u;                  // 3,145,728 (V third unused)
  unsigned short* attnb = u + 3145728;       // 4,194,304
  unsigned short* xnb = u + 7340032;         // 1,048,576
  unsigned short* ob = u + 8388608;          // 1,048,576
  unsigned short* wqt = u + 9437184;         //   786,432
  unsigned short* wot = u + 10223616;        //   262,144
  unsigned short* upb = u + 10485760;        //   492,032
  unsigned short* vtb = u + 10977792;        // 1,048,576
  if (ws_size < (size_t)12026368 * sizeof(unsigned short)) return;  // ~24 MB

  prep_kernel<<<2545, 256, 0, stream>>>(x, ln_g, ln_b, w_qkv, w_out, up,
                                        xnb, wqt, wot, upb);
  mfma_gemm_bt<64, 64, false, true, true>
      <<<dim3(32, 24), 256, 0, stream>>>(xnb, wqt, nullptr, qkvb, vtb,
                                         2048, 512, 1536);
  fused_attn_kernel<<<dim3(8, 64), 128, 0, stream>>>(qkvb, vtb, attnb, ob);
  rpos_kernel<<<2048, 256, 0, stream>>>(attnb, upb, ob);
  mfma_gemm_bt<64, 32, true, false, false>
      <<<dim3(32, 16), 256, 0, stream>>>(ob, wot, b_out, out, nullptr,
                                         2048, 512, 512);
}